// Round 7
// baseline (803.616 us; speedup 1.0000x reference)
//
#include <hip/hip_runtime.h>

#define TOK 49
#define DIM 128
#define NHEAD 4
#define NWIN 1024
#define SCALE 0.17677669529663687f  // 1/sqrt(32)

typedef __bf16 bf16x8 __attribute__((ext_vector_type(8)));
typedef short s16x4 __attribute__((ext_vector_type(4)));
typedef float f32x4 __attribute__((ext_vector_type(4)));
typedef unsigned short u16;
typedef unsigned int u32;

#if defined(__HIP_DEVICE_COMPILE__)
#define MFMA16(a, b, c) __builtin_amdgcn_mfma_f32_16x16x16bf16_1k(a, b, c, 0, 0, 0)
#define MFMA32(a, b, c) __builtin_amdgcn_mfma_f32_16x16x32_bf16(a, b, c, 0, 0, 0)
#else
__device__ inline f32x4 MFMA16(s16x4, s16x4, f32x4 c) { return c; }
__device__ inline f32x4 MFMA32(bf16x8, bf16x8, f32x4 c) { return c; }
#endif

__device__ __forceinline__ int xo256(int row, int kbyte) {
    return row * 256 + (kbyte ^ ((row & 7) << 4));
}
__device__ __forceinline__ u16 bfbits(float x) {
    __bf16 t = (__bf16)x;
    return __builtin_bit_cast(u16, t);
}
__device__ __forceinline__ float bf2f(u16 x) {
    u32 u = ((u32)x) << 16;
    return __builtin_bit_cast(float, u);
}
__device__ __forceinline__ bf16x8 cvt8(const float* __restrict__ p) {
    float4 a = *reinterpret_cast<const float4*>(p);
    float4 bq = *reinterpret_cast<const float4*>(p + 4);
    bf16x8 r;
    r[0] = (__bf16)a.x; r[1] = (__bf16)a.y; r[2] = (__bf16)a.z; r[3] = (__bf16)a.w;
    r[4] = (__bf16)bq.x; r[5] = (__bf16)bq.y; r[6] = (__bf16)bq.z; r[7] = (__bf16)bq.w;
    return r;
}
__device__ __forceinline__ bf16x8 cvt8s(const float* __restrict__ p, float s) {
    float4 a = *reinterpret_cast<const float4*>(p);
    float4 bq = *reinterpret_cast<const float4*>(p + 4);
    bf16x8 r;
    r[0] = (__bf16)(a.x * s); r[1] = (__bf16)(a.y * s);
    r[2] = (__bf16)(a.z * s); r[3] = (__bf16)(a.w * s);
    r[4] = (__bf16)(bq.x * s); r[5] = (__bf16)(bq.y * s);
    r[6] = (__bf16)(bq.z * s); r[7] = (__bf16)(bq.w * s);
    return r;
}
__device__ __forceinline__ s16x4 pack4(const f32x4& a) {
    s16x4 r;
    r[0] = (short)bfbits(a[0]); r[1] = (short)bfbits(a[1]);
    r[2] = (short)bfbits(a[2]); r[3] = (short)bfbits(a[3]);
    return r;
}
__device__ __forceinline__ s16x4 pack4s(const f32x4& a, float s) {
    s16x4 r;
    r[0] = (short)bfbits(a[0] * s); r[1] = (short)bfbits(a[1] * s);
    r[2] = (short)bfbits(a[2] * s); r[3] = (short)bfbits(a[3] * s);
    return r;
}

// mask table: [NWIN][64][64] bf16 (zero-padded)
__global__ void mask_pre_kernel(const float* __restrict__ mask, u16* __restrict__ tbl) {
    const int idx = blockIdx.x * 256 + threadIdx.x;  // exactly NWIN*64*64
    const int w = idx >> 12, l = (idx >> 6) & 63, m = idx & 63;
    u16 v = 0;
    if (l < TOK && m < TOK) v = bfbits(mask[(w * TOK + l) * TOK + m]);
    tbl[idx] = v;
}

// bias table: [NHEAD][64][64] f32 (zero-padded)
__global__ void bias_pre_kernel(const float* __restrict__ rel, float* __restrict__ biasT) {
    const int idx = blockIdx.x * 256 + threadIdx.x;  // exactly NHEAD*64*64
    const int h = idx >> 12, l = (idx >> 6) & 63, m = idx & 63;
    float v = 0.0f;
    if (l < TOK && m < TOK) {
        const int dl = l / 7 - m / 7 + 6;
        const int dc = l % 7 - m % 7 + 6;
        v = rel[(dl * 13 + dc) * NHEAD + h];
    }
    biasT[idx] = v;
}

// weights -> bf16 row-major [4][128][128]: 0=Wq*SCALE, 1=Wk, 2=Wv, 3=Wo
__global__ void wcvt_kernel(const float* __restrict__ Wq, const float* __restrict__ Wk,
                            const float* __restrict__ Wv, const float* __restrict__ Wo,
                            u16* __restrict__ tbl) {
    const int idx = blockIdx.x * 256 + threadIdx.x;  // exactly 4*128*128
    const int mat = idx >> 14, e = idx & 16383;      // mat uniform per block
    float v;
    if (mat == 0)      v = Wq[e] * SCALE;
    else if (mat == 1) v = Wk[e];
    else if (mat == 2) v = Wv[e];
    else               v = Wo[e];
    tbl[idx] = bfbits(v);
}

// MODE 0: bf16 weight/mask tables from ws. MODE 1: everything from fp32 inputs.
template <int MODE>
__global__ __launch_bounds__(512, 4) void winattn_kernel(
    const float* __restrict__ q, const float* __restrict__ k, const float* __restrict__ v,
    const float* __restrict__ mask, const float* __restrict__ Wq, const float* __restrict__ Wk,
    const float* __restrict__ Wv, const float* __restrict__ Wo, const float* __restrict__ bo,
    const u16* __restrict__ wtbl, const u16* __restrict__ mtbl, const float* __restrict__ btbl,
    float* __restrict__ out)
{
    __shared__ __align__(16) char OH[16384];  // [64 l][128 d] bf16, xo256-swizzled
    const int tid = threadIdx.x;
    const int wave = tid >> 6;        // 0..7
    const int lane = tid & 63;
    const int l16 = lane & 15;
    const int k8 = lane >> 4;
    const int b = blockIdx.x;
    const int h = wave >> 1;          // head
    const int jj = wave & 1;          // l-half: tiles {2jj, 2jj+1}

    const float* qp = q + (size_t)b * (TOK * DIM);
    const float* kp = k + (size_t)b * (TOK * DIM);
    const float* vp = v + (size_t)b * (TOK * DIM);
    float* op = out + (size_t)b * (TOK * DIM);

    // bf16 weight fragment: one aligned 16B load (row-major [mat][128][128])
    auto ldw = [&](int mat, int row, int kk) -> bf16x8 {
        return *reinterpret_cast<const bf16x8*>(
            reinterpret_cast<const __bf16*>(wtbl) + (mat << 14) + row * DIM + kk * 32 + k8 * 8);
    };

    // ===== phase 1: Q^T proj (this wave's 2 l-tiles), swapped, C rows = d ====
    s16x4 qf[2][2];  // [d-chunk t][our l-tile n]
    {
        f32x4 acc[2][2];
        #pragma unroll
        for (int t = 0; t < 2; ++t)
            #pragma unroll
            for (int n = 0; n < 2; ++n) acc[t][n] = f32x4{0.f, 0.f, 0.f, 0.f};
        #pragma unroll
        for (int kk = 0; kk < 4; ++kk) {
            bf16x8 wa[2], xb[2];
            #pragma unroll
            for (int t = 0; t < 2; ++t)
                wa[t] = (MODE == 0) ? ldw(0, h * 32 + t * 16 + l16, kk)
                                    : cvt8s(Wq + (h * 32 + t * 16 + l16) * DIM + kk * 32 + k8 * 8, SCALE);
            #pragma unroll
            for (int n = 0; n < 2; ++n) {
                int tok = (jj * 2 + n) * 16 + l16; tok = tok < TOK ? tok : TOK - 1;
                xb[n] = cvt8(qp + tok * DIM + kk * 32 + k8 * 8);
            }
            #pragma unroll
            for (int t = 0; t < 2; ++t)
                #pragma unroll
                for (int n = 0; n < 2; ++n) acc[t][n] = MFMA32(wa[t], xb[n], acc[t][n]);
        }
        #pragma unroll
        for (int t = 0; t < 2; ++t)
            #pragma unroll
            for (int n = 0; n < 2; ++n) qf[t][n] = pack4(acc[t][n]);
    }

    // ===== phase 2: K^T proj (FULL m range; duplicated across the head pair) =
    s16x4 kf[2][4];  // [d-chunk t][m-tile mi]
    {
        f32x4 acc[2][4];
        #pragma unroll
        for (int t = 0; t < 2; ++t)
            #pragma unroll
            for (int mi = 0; mi < 4; ++mi) acc[t][mi] = f32x4{0.f, 0.f, 0.f, 0.f};
        #pragma unroll
        for (int kk = 0; kk < 4; ++kk) {
            bf16x8 wa[2], xb[4];
            #pragma unroll
            for (int t = 0; t < 2; ++t)
                wa[t] = (MODE == 0) ? ldw(1, h * 32 + t * 16 + l16, kk)
                                    : cvt8(Wk + (h * 32 + t * 16 + l16) * DIM + kk * 32 + k8 * 8);
            #pragma unroll
            for (int mi = 0; mi < 4; ++mi) {
                int tok = mi * 16 + l16; tok = tok < TOK ? tok : TOK - 1;
                xb[mi] = cvt8(kp + tok * DIM + kk * 32 + k8 * 8);
            }
            #pragma unroll
            for (int t = 0; t < 2; ++t)
                #pragma unroll
                for (int mi = 0; mi < 4; ++mi) acc[t][mi] = MFMA32(wa[t], xb[mi], acc[t][mi]);
        }
        #pragma unroll
        for (int t = 0; t < 2; ++t)
            #pragma unroll
            for (int mi = 0; mi < 4; ++mi) kf[t][mi] = pack4(acc[t][mi]);
    }

    // ===== phase 3: V proj (standard, C rows = m; full m, duplicated) ========
    s16x4 vf[4][2];  // [m-chunk mi][d-tile nn]
    {
        f32x4 acc[4][2];
        #pragma unroll
        for (int mi = 0; mi < 4; ++mi)
            #pragma unroll
            for (int nn = 0; nn < 2; ++nn) acc[mi][nn] = f32x4{0.f, 0.f, 0.f, 0.f};
        #pragma unroll
        for (int kk = 0; kk < 4; ++kk) {
            bf16x8 xa[4], wb[2];
            #pragma unroll
            for (int mi = 0; mi < 4; ++mi) {
                int tok = mi * 16 + l16; tok = tok < TOK ? tok : TOK - 1;
                xa[mi] = cvt8(vp + tok * DIM + kk * 32 + k8 * 8);
            }
            #pragma unroll
            for (int nn = 0; nn < 2; ++nn)
                wb[nn] = (MODE == 0) ? ldw(2, h * 32 + nn * 16 + l16, kk)
                                     : cvt8(Wv + (h * 32 + nn * 16 + l16) * DIM + kk * 32 + k8 * 8);
            #pragma unroll
            for (int mi = 0; mi < 4; ++mi)
                #pragma unroll
                for (int nn = 0; nn < 2; ++nn) acc[mi][nn] = MFMA32(xa[mi], wb[nn], acc[mi][nn]);
        }
        #pragma unroll
        for (int mi = 0; mi < 4; ++mi)
            #pragma unroll
            for (int nn = 0; nn < 2; ++nn) vf[mi][nn] = pack4(acc[mi][nn]);
    }

    // ===== phase 4: QK^T via MFMA16 (lane-local operands) ====================
    f32x4 e[4][2];  // C: row = m = mi*16 + k8*4 + r, col = l = (jj*2+n)*16 + l16
    #pragma unroll
    for (int mi = 0; mi < 4; ++mi) {
        #pragma unroll
        for (int n = 0; n < 2; ++n) {
            f32x4 c = {0.f, 0.f, 0.f, 0.f};
            c = MFMA16(kf[0][mi], qf[0][n], c);
            e[mi][n] = MFMA16(kf[1][mi], qf[1][n], c);
        }
    }
    // qf/kf dead.

    // ===== phase 5: bias + mask + softmax over m; pack P -> pf ===============
    s16x4 pf[4][2];
    {
        const float* brow = btbl + ((size_t)h << 12);
        const u16* mrow = (MODE == 0) ? mtbl + ((size_t)(b & (NWIN - 1)) << 12) : nullptr;
        const float* mp = mask + (size_t)(b & (NWIN - 1)) * (TOK * TOK);
        #pragma unroll
        for (int n = 0; n < 2; ++n) {
            const int l = (jj * 2 + n) * 16 + l16;
            const bool lv = l < TOK;
            #pragma unroll
            for (int mi = 0; mi < 4; ++mi) {
                const int m0 = mi * 16 + k8 * 4;
                const float4 bg = *reinterpret_cast<const float4*>(brow + l * 64 + m0);
                const float bgv[4] = {bg.x, bg.y, bg.z, bg.w};
                float mkf[4];
                if constexpr (MODE == 0) {
                    const uint2 mraw = *reinterpret_cast<const uint2*>(mrow + l * 64 + m0);
                    mkf[0] = bf2f((u16)(mraw.x & 0xffffu));
                    mkf[1] = bf2f((u16)(mraw.x >> 16));
                    mkf[2] = bf2f((u16)(mraw.y & 0xffffu));
                    mkf[3] = bf2f((u16)(mraw.y >> 16));
                } else {
                    #pragma unroll
                    for (int r = 0; r < 4; ++r) {
                        const int m = m0 + r;
                        mkf[r] = (lv && m < TOK) ? mp[l * TOK + m] : 0.0f;
                    }
                }
                #pragma unroll
                for (int r = 0; r < 4; ++r) {
                    const int m = m0 + r;
                    float val = -1e30f;
                    if (lv && m < TOK) val = e[mi][n][r] + bgv[r] + mkf[r];
                    e[mi][n][r] = val;
                }
            }
            float mx = -1e30f;
            #pragma unroll
            for (int mi = 0; mi < 4; ++mi)
                #pragma unroll
                for (int r = 0; r < 4; ++r) mx = fmaxf(mx, e[mi][n][r]);
            mx = fmaxf(mx, __shfl_xor(mx, 16));
            mx = fmaxf(mx, __shfl_xor(mx, 32));
            float s = 0.f;
            #pragma unroll
            for (int mi = 0; mi < 4; ++mi) {
                #pragma unroll
                for (int r = 0; r < 4; ++r) {
                    const float p = __expf(e[mi][n][r] - mx);
                    e[mi][n][r] = p;
                    s += p;
                }
            }
            s += __shfl_xor(s, 16);
            s += __shfl_xor(s, 32);
            const float rs = 1.0f / s;
            #pragma unroll
            for (int mi = 0; mi < 4; ++mi) pf[mi][n] = pack4s(e[mi][n], rs);
        }
    }

    // ===== phase 6: PV via MFMA16 ============================================
    f32x4 o_[2][2];  // C: row = l = (jj*2+n)*16 + k8*4 + r, col = d = h*32+nn*16+l16
    #pragma unroll
    for (int n = 0; n < 2; ++n) {
        #pragma unroll
        for (int nn = 0; nn < 2; ++nn) {
            f32x4 c = {0.f, 0.f, 0.f, 0.f};
            #pragma unroll
            for (int mi = 0; mi < 4; ++mi) c = MFMA16(pf[mi][n], vf[mi][nn], c);
            o_[n][nn] = c;
        }
    }

    // ===== phase 7: OH write; Wo frags load under the barrier ================
    #pragma unroll
    for (int n = 0; n < 2; ++n) {
        #pragma unroll
        for (int nn = 0; nn < 2; ++nn) {
            const int d = h * 32 + nn * 16 + l16;
            #pragma unroll
            for (int r = 0; r < 4; ++r) {
                const int row = (jj * 2 + n) * 16 + k8 * 4 + r;
                *reinterpret_cast<u16*>(OH + xo256(row, d * 2)) = bfbits(o_[n][nn][r]);
            }
        }
    }
    bf16x8 aw[4];  // this wave's o-tile = rows wave*16..+16 of Wo
    #pragma unroll
    for (int kk = 0; kk < 4; ++kk)
        aw[kk] = (MODE == 0) ? ldw(3, wave * 16 + l16, kk)
                             : cvt8(Wo + (wave * 16 + l16) * DIM + kk * 32 + k8 * 8);
    __syncthreads();

    // ===== phase 8: out-proj swapped: out^T[o][l]; float4 store + bias =======
    #pragma unroll
    for (int ni = 0; ni < 4; ++ni) {
        const int l = ni * 16 + l16;
        bf16x8 bx[4];
        #pragma unroll
        for (int kk = 0; kk < 4; ++kk)
            bx[kk] = *reinterpret_cast<const bf16x8*>(OH + xo256(l, kk * 64 + k8 * 16));
        f32x4 c = {0.f, 0.f, 0.f, 0.f};
        #pragma unroll
        for (int kk = 0; kk < 4; ++kk) c = MFMA32(aw[kk], bx[kk], c);
        if (l < TOK) {
            const int o0 = wave * 16 + k8 * 4;
            const float4 bias = *reinterpret_cast<const float4*>(bo + o0);
            float4 st;
            st.x = c[0] + bias.x;
            st.y = c[1] + bias.y;
            st.z = c[2] + bias.z;
            st.w = c[3] + bias.w;
            *reinterpret_cast<float4*>(op + l * DIM + o0) = st;
        }
    }
}

extern "C" void kernel_launch(void* const* d_in, const int* in_sizes, int n_in,
                              void* d_out, int out_size, void* d_ws, size_t ws_size,
                              hipStream_t stream) {
    const float* q    = (const float*)d_in[0];
    const float* k    = (const float*)d_in[1];
    const float* v    = (const float*)d_in[2];
    const float* mask = (const float*)d_in[3];
    const float* Wq   = (const float*)d_in[4];
    const float* Wk   = (const float*)d_in[5];
    const float* Wv   = (const float*)d_in[6];
    const float* Wo   = (const float*)d_in[7];
    const float* bo   = (const float*)d_in[8];
    const float* rel  = (const float*)d_in[9];
    float* out = (float*)d_out;

    const int B = in_sizes[0] / (TOK * DIM);  // 8192 windows
    const size_t MASK_BYTES = (size_t)NWIN * 64 * 64 * sizeof(u16);    // 8 MB
    const size_t BIAS_BYTES = (size_t)NHEAD * 64 * 64 * sizeof(float); // 64 KB
    const size_t W_BYTES    = (size_t)4 * DIM * DIM * sizeof(u16);     // 128 KB

    if (ws_size >= MASK_BYTES + BIAS_BYTES + W_BYTES) {
        u16* mtbl   = (u16*)d_ws;
        float* btbl = (float*)((char*)d_ws + MASK_BYTES);
        u16* wtbl   = (u16*)((char*)d_ws + MASK_BYTES + BIAS_BYTES);
        mask_pre_kernel<<<dim3(NWIN * 64 * 64 / 256), dim3(256), 0, stream>>>(mask, mtbl);
        bias_pre_kernel<<<dim3(NHEAD * 64 * 64 / 256), dim3(256), 0, stream>>>(rel, btbl);
        wcvt_kernel<<<dim3(4 * DIM * DIM / 256), dim3(256), 0, stream>>>(Wq, Wk, Wv, Wo, wtbl);
        winattn_kernel<0><<<dim3(B), dim3(512), 0, stream>>>(q, k, v, mask, Wq, Wk, Wv, Wo,
                                                             bo, wtbl, mtbl, btbl, out);
    } else {
        float* btbl = (float*)d_ws;  // 64 KB
        bias_pre_kernel<<<dim3(NHEAD * 64 * 64 / 256), dim3(256), 0, stream>>>(rel, btbl);
        winattn_kernel<1><<<dim3(B), dim3(512), 0, stream>>>(q, k, v, mask, Wq, Wk, Wv, Wo,
                                                             bo, nullptr, nullptr, btbl, out);
    }
}

// Round 8
// 360.449 us; speedup vs baseline: 2.2295x; 2.2295x over previous
//
#include <hip/hip_runtime.h>

#define TOK 49
#define DIM 128
#define NHEAD 4
#define NWIN 1024
#define SCALE 0.17677669529663687f  // 1/sqrt(32)

typedef __bf16 bf16x8 __attribute__((ext_vector_type(8)));
typedef short s16x4 __attribute__((ext_vector_type(4)));
typedef float f32x4 __attribute__((ext_vector_type(4)));
typedef unsigned short u16;
typedef unsigned int u32;

#if defined(__HIP_DEVICE_COMPILE__)
#define MFMA16(a, b, c) __builtin_amdgcn_mfma_f32_16x16x16bf16_1k(a, b, c, 0, 0, 0)
#define MFMA32(a, b, c) __builtin_amdgcn_mfma_f32_16x16x32_bf16(a, b, c, 0, 0, 0)
#else
__device__ inline f32x4 MFMA16(s16x4, s16x4, f32x4 c) { return c; }
__device__ inline f32x4 MFMA32(bf16x8, bf16x8, f32x4 c) { return c; }
#endif

__device__ __forceinline__ int xo256(int row, int kbyte) {
    return row * 256 + (kbyte ^ ((row & 7) << 4));
}
__device__ __forceinline__ u16 bfbits(float x) {
    __bf16 t = (__bf16)x;
    return __builtin_bit_cast(u16, t);
}
__device__ __forceinline__ float bf2f(u16 x) {
    u32 u = ((u32)x) << 16;
    return __builtin_bit_cast(float, u);
}
__device__ __forceinline__ bf16x8 cvt8(const float* __restrict__ p) {
    float4 a = *reinterpret_cast<const float4*>(p);
    float4 bq = *reinterpret_cast<const float4*>(p + 4);
    bf16x8 r;
    r[0] = (__bf16)a.x; r[1] = (__bf16)a.y; r[2] = (__bf16)a.z; r[3] = (__bf16)a.w;
    r[4] = (__bf16)bq.x; r[5] = (__bf16)bq.y; r[6] = (__bf16)bq.z; r[7] = (__bf16)bq.w;
    return r;
}
__device__ __forceinline__ bf16x8 cvt8s(const float* __restrict__ p, float s) {
    float4 a = *reinterpret_cast<const float4*>(p);
    float4 bq = *reinterpret_cast<const float4*>(p + 4);
    bf16x8 r;
    r[0] = (__bf16)(a.x * s); r[1] = (__bf16)(a.y * s);
    r[2] = (__bf16)(a.z * s); r[3] = (__bf16)(a.w * s);
    r[4] = (__bf16)(bq.x * s); r[5] = (__bf16)(bq.y * s);
    r[6] = (__bf16)(bq.z * s); r[7] = (__bf16)(bq.w * s);
    return r;
}
__device__ __forceinline__ s16x4 pack4(const f32x4& a) {
    s16x4 r;
    r[0] = (short)bfbits(a[0]); r[1] = (short)bfbits(a[1]);
    r[2] = (short)bfbits(a[2]); r[3] = (short)bfbits(a[3]);
    return r;
}
__device__ __forceinline__ s16x4 pack4s(const f32x4& a, float s) {
    s16x4 r;
    r[0] = (short)bfbits(a[0] * s); r[1] = (short)bfbits(a[1] * s);
    r[2] = (short)bfbits(a[2] * s); r[3] = (short)bfbits(a[3] * s);
    return r;
}

// fused mask+bias table: [NWIN][NHEAD][64][64] bf16, zero-padded past 49
__global__ void fused_pre_kernel(const float* __restrict__ mask, const float* __restrict__ rel,
                                 u16* __restrict__ tbl) {
    const int idx = blockIdx.x * 256 + threadIdx.x;  // exactly NWIN*NHEAD*64*64
    const int w = idx >> 14, h = (idx >> 12) & 3, l = (idx >> 6) & 63, m = idx & 63;
    float v = 0.0f;
    if (l < TOK && m < TOK) {
        const int dl = l / 7 - m / 7 + 6;
        const int dc = l % 7 - m % 7 + 6;
        v = mask[(w * TOK + l) * TOK + m] + rel[(dl * 13 + dc) * NHEAD + h];
    }
    tbl[idx] = bfbits(v);
}

// bias table (MODE1 fallback): [NHEAD][64][64] f32, zero-padded
__global__ void bias_pre_kernel(const float* __restrict__ rel, float* __restrict__ biasT) {
    const int idx = blockIdx.x * 256 + threadIdx.x;
    const int h = idx >> 12, l = (idx >> 6) & 63, m = idx & 63;
    float v = 0.0f;
    if (l < TOK && m < TOK) {
        const int dl = l / 7 - m / 7 + 6;
        const int dc = l % 7 - m % 7 + 6;
        v = rel[(dl * 13 + dc) * NHEAD + h];
    }
    biasT[idx] = v;
}

// weights -> bf16 row-major [4][128][128]: 0=Wq*SCALE, 1=Wk, 2=Wv, 3=Wo
__global__ void wcvt_kernel(const float* __restrict__ Wq, const float* __restrict__ Wk,
                            const float* __restrict__ Wv, const float* __restrict__ Wo,
                            u16* __restrict__ tbl) {
    const int idx = blockIdx.x * 256 + threadIdx.x;  // exactly 4*128*128
    const int mat = idx >> 14, e = idx & 16383;
    float v;
    if (mat == 0)      v = Wq[e] * SCALE;
    else if (mat == 1) v = Wk[e];
    else if (mat == 2) v = Wv[e];
    else               v = Wo[e];
    tbl[idx] = bfbits(v);
}

// MODE 0: bf16 weight + fused mask/bias tables from ws.
// MODE 1: weights/mask from fp32 inputs, bias from small f32 table.
template <int MODE>
__global__ __launch_bounds__(256, 4) void winattn_kernel(
    const float* __restrict__ q, const float* __restrict__ k, const float* __restrict__ v,
    const float* __restrict__ mask, const float* __restrict__ Wq, const float* __restrict__ Wk,
    const float* __restrict__ Wv, const float* __restrict__ Wo, const float* __restrict__ bo,
    const u16* __restrict__ wtbl, const u16* __restrict__ fmtbl, const float* __restrict__ btbl,
    float* __restrict__ out)
{
    __shared__ __align__(16) char LA[16384];  // [64][128] bf16 swizzled: q, then v
    __shared__ __align__(16) char LB[16384];  // [64][128] bf16 swizzled: k, then OH
    const int tid = threadIdx.x;
    const int wave = tid >> 6;
    const int lane = tid & 63;
    const int l16 = lane & 15;
    const int k8 = lane >> 4;
    const int b = blockIdx.x;
    const int h = wave;  // wave == head

    const float* qp = q + (size_t)b * (TOK * DIM);
    const float* kp = k + (size_t)b * (TOK * DIM);
    const float* vp = v + (size_t)b * (TOK * DIM);
    float* op = out + (size_t)b * (TOK * DIM);

    // bf16 weight fragment: one aligned 16B load (row-major [mat][128][128])
    auto ldw = [&](int mat, int row, int kk) -> bf16x8 {
        return *reinterpret_cast<const bf16x8*>(
            reinterpret_cast<const __bf16*>(wtbl) + (mat << 14) + row * DIM + kk * 32 + k8 * 8);
    };
    // x fragment from LDS: 16B ds_read_b128
    auto ldx = [&](const char* buf, int row, int kk) -> bf16x8 {
        return *reinterpret_cast<const bf16x8*>(buf + xo256(row, kk * 64 + k8 * 16));
    };

    // ===== stage q -> LA, k -> LB: coalesced batch loads, bf16 swizzled =====
    // thread t writes float4-slots t, t+256, ... (row = idx/32, 16B f32 chunk = idx%32)
    {
        float4 tq[8], tk[8];
        #pragma unroll
        for (int p = 0; p < 8; ++p) {
            const int idx = p * 256 + tid;
            const int row = idx >> 5;
            const int c4 = (idx & 31) * 4;
            if (row < TOK) {
                tq[p] = *reinterpret_cast<const float4*>(qp + row * DIM + c4);
                tk[p] = *reinterpret_cast<const float4*>(kp + row * DIM + c4);
            } else {
                tq[p] = float4{0.f, 0.f, 0.f, 0.f};
                tk[p] = float4{0.f, 0.f, 0.f, 0.f};
            }
        }
        #pragma unroll
        for (int p = 0; p < 8; ++p) {
            const int idx = p * 256 + tid;
            const int row = idx >> 5;
            const int kb = (idx & 31) * 8;  // byte offset of 4 bf16
            uint2 pq, pk2;
            pq.x  = (u32)bfbits(tq[p].x) | ((u32)bfbits(tq[p].y) << 16);
            pq.y  = (u32)bfbits(tq[p].z) | ((u32)bfbits(tq[p].w) << 16);
            pk2.x = (u32)bfbits(tk[p].x) | ((u32)bfbits(tk[p].y) << 16);
            pk2.y = (u32)bfbits(tk[p].z) | ((u32)bfbits(tk[p].w) << 16);
            *reinterpret_cast<uint2*>(LA + xo256(row, kb)) = pq;
            *reinterpret_cast<uint2*>(LB + xo256(row, kb)) = pk2;
        }
    }
    __syncthreads();  // barrier 1: q/k staged

    // issue v loads now: latency hides under q/k projections
    float4 tv[8];
    #pragma unroll
    for (int p = 0; p < 8; ++p) {
        const int idx = p * 256 + tid;
        const int row = idx >> 5;
        const int c4 = (idx & 31) * 4;
        tv[p] = (row < TOK) ? *reinterpret_cast<const float4*>(vp + row * DIM + c4)
                            : float4{0.f, 0.f, 0.f, 0.f};
    }

    // ===== proj q (swapped W.X^T, C rows = d), x-frags from LDS ==============
    s16x4 qf[2][4], kf[2][4];
    {
        f32x4 acc[2][4];
        #pragma unroll
        for (int t = 0; t < 2; ++t)
            #pragma unroll
            for (int ni = 0; ni < 4; ++ni) acc[t][ni] = f32x4{0.f, 0.f, 0.f, 0.f};
        #pragma unroll
        for (int kk = 0; kk < 4; ++kk) {
            bf16x8 wa[2], xb[4];
            #pragma unroll
            for (int t = 0; t < 2; ++t)
                wa[t] = (MODE == 0) ? ldw(0, h * 32 + t * 16 + l16, kk)
                                    : cvt8s(Wq + (h * 32 + t * 16 + l16) * DIM + kk * 32 + k8 * 8, SCALE);
            #pragma unroll
            for (int ni = 0; ni < 4; ++ni) xb[ni] = ldx(LA, ni * 16 + l16, kk);
            #pragma unroll
            for (int t = 0; t < 2; ++t)
                #pragma unroll
                for (int ni = 0; ni < 4; ++ni) acc[t][ni] = MFMA32(wa[t], xb[ni], acc[t][ni]);
        }
        #pragma unroll
        for (int t = 0; t < 2; ++t)
            #pragma unroll
            for (int ni = 0; ni < 4; ++ni) qf[t][ni] = pack4(acc[t][ni]);
    }
    // ===== proj k =====
    {
        f32x4 acc[2][4];
        #pragma unroll
        for (int t = 0; t < 2; ++t)
            #pragma unroll
            for (int mi = 0; mi < 4; ++mi) acc[t][mi] = f32x4{0.f, 0.f, 0.f, 0.f};
        #pragma unroll
        for (int kk = 0; kk < 4; ++kk) {
            bf16x8 wa[2], xb[4];
            #pragma unroll
            for (int t = 0; t < 2; ++t)
                wa[t] = (MODE == 0) ? ldw(1, h * 32 + t * 16 + l16, kk)
                                    : cvt8(Wk + (h * 32 + t * 16 + l16) * DIM + kk * 32 + k8 * 8);
            #pragma unroll
            for (int mi = 0; mi < 4; ++mi) xb[mi] = ldx(LB, mi * 16 + l16, kk);
            #pragma unroll
            for (int t = 0; t < 2; ++t)
                #pragma unroll
                for (int mi = 0; mi < 4; ++mi) acc[t][mi] = MFMA32(wa[t], xb[mi], acc[t][mi]);
        }
        #pragma unroll
        for (int t = 0; t < 2; ++t)
            #pragma unroll
            for (int mi = 0; mi < 4; ++mi) kf[t][mi] = pack4(acc[t][mi]);
    }
    __syncthreads();  // barrier 2: all reads of LA/LB (q,k frags) complete

    // ===== write v -> LA (loads issued long ago) =====
    #pragma unroll
    for (int p = 0; p < 8; ++p) {
        const int idx = p * 256 + tid;
        const int row = idx >> 5;
        const int kb = (idx & 31) * 8;
        uint2 pv;
        pv.x = (u32)bfbits(tv[p].x) | ((u32)bfbits(tv[p].y) << 16);
        pv.y = (u32)bfbits(tv[p].z) | ((u32)bfbits(tv[p].w) << 16);
        *reinterpret_cast<uint2*>(LA + xo256(row, kb)) = pv;
    }
    __syncthreads();  // barrier 3: v staged

    // ===== QK^T + softmax fused per l-tile (e never fully materialized) =====
    s16x4 pf[4][4];  // [m-chunk mi][l-tile ni]
    {
        const u16* frow = (MODE == 0)
            ? fmtbl + ((((size_t)(b & (NWIN - 1)) * NHEAD) + h) << 12) : nullptr;
        const float* brow = (MODE == 1) ? btbl + ((size_t)h << 12) : nullptr;
        const float* mp = mask + (size_t)(b & (NWIN - 1)) * (TOK * TOK);
        #pragma unroll
        for (int ni = 0; ni < 4; ++ni) {
            f32x4 ec[4];  // E^T column block for this l-tile
            #pragma unroll
            for (int mi = 0; mi < 4; ++mi) {
                f32x4 c = {0.f, 0.f, 0.f, 0.f};
                c = MFMA16(kf[0][mi], qf[0][ni], c);
                ec[mi] = MFMA16(kf[1][mi], qf[1][ni], c);
            }
            const int l = ni * 16 + l16;
            const bool lv = l < TOK;
            #pragma unroll
            for (int mi = 0; mi < 4; ++mi) {
                const int m0 = mi * 16 + k8 * 4;
                float ad[4];
                if constexpr (MODE == 0) {
                    const uint2 raw = *reinterpret_cast<const uint2*>(frow + l * 64 + m0);
                    ad[0] = bf2f((u16)(raw.x & 0xffffu));
                    ad[1] = bf2f((u16)(raw.x >> 16));
                    ad[2] = bf2f((u16)(raw.y & 0xffffu));
                    ad[3] = bf2f((u16)(raw.y >> 16));
                } else {
                    const float4 bg = *reinterpret_cast<const float4*>(brow + l * 64 + m0);
                    ad[0] = bg.x; ad[1] = bg.y; ad[2] = bg.z; ad[3] = bg.w;
                    #pragma unroll
                    for (int r = 0; r < 4; ++r) {
                        const int m = m0 + r;
                        if (lv && m < TOK) ad[r] += mp[l * TOK + m];
                    }
                }
                #pragma unroll
                for (int r = 0; r < 4; ++r) {
                    const int m = m0 + r;
                    ec[mi][r] = (lv && m < TOK) ? ec[mi][r] + ad[r] : -1e30f;
                }
            }
            float mx = -1e30f;
            #pragma unroll
            for (int mi = 0; mi < 4; ++mi)
                #pragma unroll
                for (int r = 0; r < 4; ++r) mx = fmaxf(mx, ec[mi][r]);
            mx = fmaxf(mx, __shfl_xor(mx, 16));
            mx = fmaxf(mx, __shfl_xor(mx, 32));
            float s = 0.f;
            #pragma unroll
            for (int mi = 0; mi < 4; ++mi) {
                #pragma unroll
                for (int r = 0; r < 4; ++r) {
                    const float p = __expf(ec[mi][r] - mx);
                    ec[mi][r] = p;
                    s += p;
                }
            }
            s += __shfl_xor(s, 16);
            s += __shfl_xor(s, 32);
            const float rs = 1.0f / s;
            #pragma unroll
            for (int mi = 0; mi < 4; ++mi) pf[mi][ni] = pack4s(ec[mi], rs);
        }
    }
    // qf/kf dead.

    // ===== proj v (reads LA), C rows = m =====
    s16x4 vf[4][2];
    {
        f32x4 acc[4][2];
        #pragma unroll
        for (int mi = 0; mi < 4; ++mi)
            #pragma unroll
            for (int nn = 0; nn < 2; ++nn) acc[mi][nn] = f32x4{0.f, 0.f, 0.f, 0.f};
        #pragma unroll
        for (int kk = 0; kk < 4; ++kk) {
            bf16x8 xa[4], wb[2];
            #pragma unroll
            for (int mi = 0; mi < 4; ++mi) xa[mi] = ldx(LA, mi * 16 + l16, kk);
            #pragma unroll
            for (int nn = 0; nn < 2; ++nn)
                wb[nn] = (MODE == 0) ? ldw(2, h * 32 + nn * 16 + l16, kk)
                                     : cvt8(Wv + (h * 32 + nn * 16 + l16) * DIM + kk * 32 + k8 * 8);
            #pragma unroll
            for (int mi = 0; mi < 4; ++mi)
                #pragma unroll
                for (int nn = 0; nn < 2; ++nn) acc[mi][nn] = MFMA32(xa[mi], wb[nn], acc[mi][nn]);
        }
        #pragma unroll
        for (int mi = 0; mi < 4; ++mi)
            #pragma unroll
            for (int nn = 0; nn < 2; ++nn) vf[mi][nn] = pack4(acc[mi][nn]);
    }

    // ===== PV via MFMA16 (lane-local) =====
    f32x4 o_[4][2];  // row = l = ni*16 + k8*4 + r, col = d = h*32 + nn*16 + l16
    #pragma unroll
    for (int ni = 0; ni < 4; ++ni) {
        #pragma unroll
        for (int nn = 0; nn < 2; ++nn) {
            f32x4 c = {0.f, 0.f, 0.f, 0.f};
            #pragma unroll
            for (int mi = 0; mi < 4; ++mi) c = MFMA16(pf[mi][ni], vf[mi][nn], c);
            o_[ni][nn] = c;
        }
    }

    // ===== OH -> LB (kf reads of LB ended before barrier 2); Wo under barrier =
    #pragma unroll
    for (int ni = 0; ni < 4; ++ni) {
        #pragma unroll
        for (int nn = 0; nn < 2; ++nn) {
            const int d = h * 32 + nn * 16 + l16;
            #pragma unroll
            for (int r = 0; r < 4; ++r) {
                const int row = ni * 16 + k8 * 4 + r;
                *reinterpret_cast<u16*>(LB + xo256(row, d * 2)) = bfbits(o_[ni][nn][r]);
            }
        }
    }
    bf16x8 aw[2][4];
    #pragma unroll
    for (int m2 = 0; m2 < 2; ++m2) {
        const int o = (wave * 2 + m2) * 16 + l16;
        #pragma unroll
        for (int kk = 0; kk < 4; ++kk)
            aw[m2][kk] = (MODE == 0) ? ldw(3, o, kk)
                                     : cvt8(Wo + o * DIM + kk * 32 + k8 * 8);
    }
    __syncthreads();  // barrier 4

    // ===== out-proj swapped: out^T[o][l]; float4 store + fused bias ==========
    #pragma unroll
    for (int ni = 0; ni < 4; ++ni) {
        const int l = ni * 16 + l16;
        bf16x8 bx[4];
        #pragma unroll
        for (int kk = 0; kk < 4; ++kk)
            bx[kk] = *reinterpret_cast<const bf16x8*>(LB + xo256(l, kk * 64 + k8 * 16));
        #pragma unroll
        for (int m2 = 0; m2 < 2; ++m2) {
            f32x4 c = {0.f, 0.f, 0.f, 0.f};
            #pragma unroll
            for (int kk = 0; kk < 4; ++kk) c = MFMA32(aw[m2][kk], bx[kk], c);
            if (l < TOK) {
                const int o0 = (wave * 2 + m2) * 16 + k8 * 4;
                const float4 bias = *reinterpret_cast<const float4*>(bo + o0);
                float4 st;
                st.x = c[0] + bias.x;
                st.y = c[1] + bias.y;
                st.z = c[2] + bias.z;
                st.w = c[3] + bias.w;
                *reinterpret_cast<float4*>(op + l * DIM + o0) = st;
            }
        }
    }
}

extern "C" void kernel_launch(void* const* d_in, const int* in_sizes, int n_in,
                              void* d_out, int out_size, void* d_ws, size_t ws_size,
                              hipStream_t stream) {
    const float* q    = (const float*)d_in[0];
    const float* k    = (const float*)d_in[1];
    const float* v    = (const float*)d_in[2];
    const float* mask = (const float*)d_in[3];
    const float* Wq   = (const float*)d_in[4];
    const float* Wk   = (const float*)d_in[5];
    const float* Wv   = (const float*)d_in[6];
    const float* Wo   = (const float*)d_in[7];
    const float* bo   = (const float*)d_in[8];
    const float* rel  = (const float*)d_in[9];
    float* out = (float*)d_out;

    const int B = in_sizes[0] / (TOK * DIM);  // 8192 windows
    const size_t FUSED_BYTES = (size_t)NWIN * NHEAD * 64 * 64 * sizeof(u16);  // 32 MB
    const size_t W_BYTES     = (size_t)4 * DIM * DIM * sizeof(u16);           // 128 KB
    const size_t BIAS_BYTES  = (size_t)NHEAD * 64 * 64 * sizeof(float);       // 64 KB

    if (ws_size >= FUSED_BYTES + W_BYTES) {
        u16* fmtbl = (u16*)d_ws;
        u16* wtbl  = (u16*)((char*)d_ws + FUSED_BYTES);
        fused_pre_kernel<<<dim3(NWIN * NHEAD * 64 * 64 / 256), dim3(256), 0, stream>>>(
            mask, rel, fmtbl);
        wcvt_kernel<<<dim3(4 * DIM * DIM / 256), dim3(256), 0, stream>>>(Wq, Wk, Wv, Wo, wtbl);
        winattn_kernel<0><<<dim3(B), dim3(256), 0, stream>>>(q, k, v, mask, Wq, Wk, Wv, Wo,
                                                             bo, wtbl, fmtbl, nullptr, out);
    } else {
        float* btbl = (float*)d_ws;  // 64 KB, proven to fit
        bias_pre_kernel<<<dim3(NHEAD * 64 * 64 / 256), dim3(256), 0, stream>>>(rel, btbl);
        winattn_kernel<1><<<dim3(B), dim3(256), 0, stream>>>(q, k, v, mask, Wq, Wk, Wv, Wo,
                                                             bo, nullptr, nullptr, btbl, out);
    }
}

// Round 9
// 337.465 us; speedup vs baseline: 2.3813x; 1.0681x over previous
//
#include <hip/hip_runtime.h>

#define TOK 49
#define DIM 128
#define NHEAD 4
#define NWIN 1024
#define SCALE 0.17677669529663687f  // 1/sqrt(32)

typedef __bf16 bf16x8 __attribute__((ext_vector_type(8)));
typedef short s16x4 __attribute__((ext_vector_type(4)));
typedef float f32x4 __attribute__((ext_vector_type(4)));
typedef unsigned short u16;
typedef unsigned int u32;

#if defined(__HIP_DEVICE_COMPILE__)
#define MFMA16(a, b, c) __builtin_amdgcn_mfma_f32_16x16x16bf16_1k(a, b, c, 0, 0, 0)
#define MFMA32(a, b, c) __builtin_amdgcn_mfma_f32_16x16x32_bf16(a, b, c, 0, 0, 0)
#else
__device__ inline f32x4 MFMA16(s16x4, s16x4, f32x4 c) { return c; }
__device__ inline f32x4 MFMA32(bf16x8, bf16x8, f32x4 c) { return c; }
#endif

__device__ __forceinline__ int xo256(int row, int kbyte) {
    return row * 256 + (kbyte ^ ((row & 7) << 4));
}
__device__ __forceinline__ u16 bfbits(float x) {
    __bf16 t = (__bf16)x;
    return __builtin_bit_cast(u16, t);
}
__device__ __forceinline__ float bf2f(u16 x) {
    u32 u = ((u32)x) << 16;
    return __builtin_bit_cast(float, u);
}
__device__ __forceinline__ bf16x8 cvt8(const float* __restrict__ p) {
    float4 a = *reinterpret_cast<const float4*>(p);
    float4 bq = *reinterpret_cast<const float4*>(p + 4);
    bf16x8 r;
    r[0] = (__bf16)a.x; r[1] = (__bf16)a.y; r[2] = (__bf16)a.z; r[3] = (__bf16)a.w;
    r[4] = (__bf16)bq.x; r[5] = (__bf16)bq.y; r[6] = (__bf16)bq.z; r[7] = (__bf16)bq.w;
    return r;
}
__device__ __forceinline__ bf16x8 cvt8s(const float* __restrict__ p, float s) {
    float4 a = *reinterpret_cast<const float4*>(p);
    float4 bq = *reinterpret_cast<const float4*>(p + 4);
    bf16x8 r;
    r[0] = (__bf16)(a.x * s); r[1] = (__bf16)(a.y * s);
    r[2] = (__bf16)(a.z * s); r[3] = (__bf16)(a.w * s);
    r[4] = (__bf16)(bq.x * s); r[5] = (__bf16)(bq.y * s);
    r[6] = (__bf16)(bq.z * s); r[7] = (__bf16)(bq.w * s);
    return r;
}
__device__ __forceinline__ s16x4 pack4(const f32x4& a) {
    s16x4 r;
    r[0] = (short)bfbits(a[0]); r[1] = (short)bfbits(a[1]);
    r[2] = (short)bfbits(a[2]); r[3] = (short)bfbits(a[3]);
    return r;
}
__device__ __forceinline__ s16x4 pack4s(const f32x4& a, float s) {
    s16x4 r;
    r[0] = (short)bfbits(a[0] * s); r[1] = (short)bfbits(a[1] * s);
    r[2] = (short)bfbits(a[2] * s); r[3] = (short)bfbits(a[3] * s);
    return r;
}

// fused mask+bias table: [NWIN][NHEAD][64][64] bf16, zero-padded past 49
__global__ void fused_pre_kernel(const float* __restrict__ mask, const float* __restrict__ rel,
                                 u16* __restrict__ tbl) {
    const int idx = blockIdx.x * 256 + threadIdx.x;  // exactly NWIN*NHEAD*64*64
    const int w = idx >> 14, h = (idx >> 12) & 3, l = (idx >> 6) & 63, m = idx & 63;
    float v = 0.0f;
    if (l < TOK && m < TOK) {
        const int dl = l / 7 - m / 7 + 6;
        const int dc = l % 7 - m % 7 + 6;
        v = mask[(w * TOK + l) * TOK + m] + rel[(dl * 13 + dc) * NHEAD + h];
    }
    tbl[idx] = bfbits(v);
}

// bias table (MODE1 fallback): [NHEAD][64][64] f32, zero-padded
__global__ void bias_pre_kernel(const float* __restrict__ rel, float* __restrict__ biasT) {
    const int idx = blockIdx.x * 256 + threadIdx.x;
    const int h = idx >> 12, l = (idx >> 6) & 63, m = idx & 63;
    float v = 0.0f;
    if (l < TOK && m < TOK) {
        const int dl = l / 7 - m / 7 + 6;
        const int dc = l % 7 - m % 7 + 6;
        v = rel[(dl * 13 + dc) * NHEAD + h];
    }
    biasT[idx] = v;
}

// weights -> bf16 row-major [4][128][128]: 0=Wq*SCALE, 1=Wk, 2=Wv, 3=Wo
__global__ void wcvt_kernel(const float* __restrict__ Wq, const float* __restrict__ Wk,
                            const float* __restrict__ Wv, const float* __restrict__ Wo,
                            u16* __restrict__ tbl) {
    const int idx = blockIdx.x * 256 + threadIdx.x;  // exactly 4*128*128
    const int mat = idx >> 14, e = idx & 16383;
    float v;
    if (mat == 0)      v = Wq[e] * SCALE;
    else if (mat == 1) v = Wk[e];
    else if (mat == 2) v = Wv[e];
    else               v = Wo[e];
    tbl[idx] = bfbits(v);
}

// MODE 0: bf16 weight + fused mask/bias tables from ws.
// MODE 1: weights/mask from fp32 inputs, bias from small f32 table.
template <int MODE>
__global__ __launch_bounds__(256, 3) void winattn_kernel(
    const float* __restrict__ q, const float* __restrict__ k, const float* __restrict__ v,
    const float* __restrict__ mask, const float* __restrict__ Wq, const float* __restrict__ Wk,
    const float* __restrict__ Wv, const float* __restrict__ Wo, const float* __restrict__ bo,
    const u16* __restrict__ wtbl, const u16* __restrict__ fmtbl, const float* __restrict__ btbl,
    float* __restrict__ out)
{
    __shared__ __align__(16) char LA[16384];  // [64][128] bf16 swizzled: q, then v
    __shared__ __align__(16) char LB[16384];  // [64][128] bf16 swizzled: k, then OH
    const int tid = threadIdx.x;
    const int wave = tid >> 6;
    const int lane = tid & 63;
    const int l16 = lane & 15;
    const int k8 = lane >> 4;
    const int b = blockIdx.x;
    const int h = wave;  // wave == head

    const float* qp = q + (size_t)b * (TOK * DIM);
    const float* kp = k + (size_t)b * (TOK * DIM);
    const float* vp = v + (size_t)b * (TOK * DIM);
    float* op = out + (size_t)b * (TOK * DIM);

    // bf16 weight fragment: one aligned 16B load (row-major [mat][128][128])
    auto ldw = [&](int mat, int row, int kk) -> bf16x8 {
        return *reinterpret_cast<const bf16x8*>(
            reinterpret_cast<const __bf16*>(wtbl) + (mat << 14) + row * DIM + kk * 32 + k8 * 8);
    };
    // x fragment from LDS: 16B ds_read_b128
    auto ldx = [&](const char* buf, int row, int kk) -> bf16x8 {
        return *reinterpret_cast<const bf16x8*>(buf + xo256(row, kk * 64 + k8 * 16));
    };

    // ===== stage q -> LA, k -> LB (one t[8] buffer, reused); v loads issued =====
    float4 tv[8];
    {
        float4 t[8];
        #pragma unroll
        for (int p = 0; p < 8; ++p) {
            const int idx = p * 256 + tid;
            const int row = idx >> 5;
            const int c4 = (idx & 31) * 4;
            t[p] = (row < TOK) ? *reinterpret_cast<const float4*>(qp + row * DIM + c4)
                               : float4{0.f, 0.f, 0.f, 0.f};
        }
        #pragma unroll
        for (int p = 0; p < 8; ++p) {
            const int idx = p * 256 + tid;
            uint2 pq;
            pq.x = (u32)bfbits(t[p].x) | ((u32)bfbits(t[p].y) << 16);
            pq.y = (u32)bfbits(t[p].z) | ((u32)bfbits(t[p].w) << 16);
            *reinterpret_cast<uint2*>(LA + xo256(idx >> 5, (idx & 31) * 8)) = pq;
        }
        #pragma unroll
        for (int p = 0; p < 8; ++p) {
            const int idx = p * 256 + tid;
            const int row = idx >> 5;
            const int c4 = (idx & 31) * 4;
            t[p] = (row < TOK) ? *reinterpret_cast<const float4*>(kp + row * DIM + c4)
                               : float4{0.f, 0.f, 0.f, 0.f};
        }
        #pragma unroll
        for (int p = 0; p < 8; ++p) {  // v loads issue before k-write; hide under proj
            const int idx = p * 256 + tid;
            const int row = idx >> 5;
            const int c4 = (idx & 31) * 4;
            tv[p] = (row < TOK) ? *reinterpret_cast<const float4*>(vp + row * DIM + c4)
                                : float4{0.f, 0.f, 0.f, 0.f};
        }
        #pragma unroll
        for (int p = 0; p < 8; ++p) {
            const int idx = p * 256 + tid;
            uint2 pk2;
            pk2.x = (u32)bfbits(t[p].x) | ((u32)bfbits(t[p].y) << 16);
            pk2.y = (u32)bfbits(t[p].z) | ((u32)bfbits(t[p].w) << 16);
            *reinterpret_cast<uint2*>(LB + xo256(idx >> 5, (idx & 31) * 8)) = pk2;
        }
    }
    __syncthreads();  // barrier 1: q/k staged

    // pack v to bf16 now: 16 regs (not 32) ride across the projections
    uint2 pv[8];
    #pragma unroll
    for (int p = 0; p < 8; ++p) {
        pv[p].x = (u32)bfbits(tv[p].x) | ((u32)bfbits(tv[p].y) << 16);
        pv[p].y = (u32)bfbits(tv[p].z) | ((u32)bfbits(tv[p].w) << 16);
    }

    // ===== proj q (swapped W.X^T, C rows = d), x-frags from LDS ==============
    s16x4 qf[2][4], kf[2][4];
    {
        f32x4 acc[2][4];
        #pragma unroll
        for (int t = 0; t < 2; ++t)
            #pragma unroll
            for (int ni = 0; ni < 4; ++ni) acc[t][ni] = f32x4{0.f, 0.f, 0.f, 0.f};
        #pragma unroll
        for (int kk = 0; kk < 4; ++kk) {
            bf16x8 wa[2], xb[4];
            #pragma unroll
            for (int t = 0; t < 2; ++t)
                wa[t] = (MODE == 0) ? ldw(0, h * 32 + t * 16 + l16, kk)
                                    : cvt8s(Wq + (h * 32 + t * 16 + l16) * DIM + kk * 32 + k8 * 8, SCALE);
            #pragma unroll
            for (int ni = 0; ni < 4; ++ni) xb[ni] = ldx(LA, ni * 16 + l16, kk);
            #pragma unroll
            for (int t = 0; t < 2; ++t)
                #pragma unroll
                for (int ni = 0; ni < 4; ++ni) acc[t][ni] = MFMA32(wa[t], xb[ni], acc[t][ni]);
        }
        #pragma unroll
        for (int t = 0; t < 2; ++t)
            #pragma unroll
            for (int ni = 0; ni < 4; ++ni) qf[t][ni] = pack4(acc[t][ni]);
    }
    // ===== proj k =====
    {
        f32x4 acc[2][4];
        #pragma unroll
        for (int t = 0; t < 2; ++t)
            #pragma unroll
            for (int mi = 0; mi < 4; ++mi) acc[t][mi] = f32x4{0.f, 0.f, 0.f, 0.f};
        #pragma unroll
        for (int kk = 0; kk < 4; ++kk) {
            bf16x8 wa[2], xb[4];
            #pragma unroll
            for (int t = 0; t < 2; ++t)
                wa[t] = (MODE == 0) ? ldw(1, h * 32 + t * 16 + l16, kk)
                                    : cvt8(Wk + (h * 32 + t * 16 + l16) * DIM + kk * 32 + k8 * 8);
            #pragma unroll
            for (int mi = 0; mi < 4; ++mi) xb[mi] = ldx(LB, mi * 16 + l16, kk);
            #pragma unroll
            for (int t = 0; t < 2; ++t)
                #pragma unroll
                for (int mi = 0; mi < 4; ++mi) acc[t][mi] = MFMA32(wa[t], xb[mi], acc[t][mi]);
        }
        #pragma unroll
        for (int t = 0; t < 2; ++t)
            #pragma unroll
            for (int mi = 0; mi < 4; ++mi) kf[t][mi] = pack4(acc[t][mi]);
    }
    __syncthreads();  // barrier 2: all reads of LA/LB (q,k frags) complete

    // ===== write v -> LA (already bf16-packed) =====
    #pragma unroll
    for (int p = 0; p < 8; ++p) {
        const int idx = p * 256 + tid;
        *reinterpret_cast<uint2*>(LA + xo256(idx >> 5, (idx & 31) * 8)) = pv[p];
    }
    __syncthreads();  // barrier 3: v staged

    // ===== QK^T + softmax fused per l-tile (e never fully materialized) =====
    s16x4 pf[4][4];  // [m-chunk mi][l-tile ni]
    {
        const u16* frow = (MODE == 0)
            ? fmtbl + ((((size_t)(b & (NWIN - 1)) * NHEAD) + h) << 12) : nullptr;
        const float* brow = (MODE == 1) ? btbl + ((size_t)h << 12) : nullptr;
        const float* mp = mask + (size_t)(b & (NWIN - 1)) * (TOK * TOK);
        #pragma unroll
        for (int ni = 0; ni < 4; ++ni) {
            f32x4 ec[4];  // E^T column block for this l-tile
            #pragma unroll
            for (int mi = 0; mi < 4; ++mi) {
                f32x4 c = {0.f, 0.f, 0.f, 0.f};
                c = MFMA16(kf[0][mi], qf[0][ni], c);
                ec[mi] = MFMA16(kf[1][mi], qf[1][ni], c);
            }
            const int l = ni * 16 + l16;
            const bool lv = l < TOK;
            #pragma unroll
            for (int mi = 0; mi < 4; ++mi) {
                const int m0 = mi * 16 + k8 * 4;
                float ad[4];
                if constexpr (MODE == 0) {
                    const uint2 raw = *reinterpret_cast<const uint2*>(frow + l * 64 + m0);
                    ad[0] = bf2f((u16)(raw.x & 0xffffu));
                    ad[1] = bf2f((u16)(raw.x >> 16));
                    ad[2] = bf2f((u16)(raw.y & 0xffffu));
                    ad[3] = bf2f((u16)(raw.y >> 16));
                } else {
                    const float4 bg = *reinterpret_cast<const float4*>(brow + l * 64 + m0);
                    ad[0] = bg.x; ad[1] = bg.y; ad[2] = bg.z; ad[3] = bg.w;
                    #pragma unroll
                    for (int r = 0; r < 4; ++r) {
                        const int m = m0 + r;
                        if (lv && m < TOK) ad[r] += mp[l * TOK + m];
                    }
                }
                #pragma unroll
                for (int r = 0; r < 4; ++r) {
                    const int m = m0 + r;
                    ec[mi][r] = (lv && m < TOK) ? ec[mi][r] + ad[r] : -1e30f;
                }
            }
            float mx = -1e30f;
            #pragma unroll
            for (int mi = 0; mi < 4; ++mi)
                #pragma unroll
                for (int r = 0; r < 4; ++r) mx = fmaxf(mx, ec[mi][r]);
            mx = fmaxf(mx, __shfl_xor(mx, 16));
            mx = fmaxf(mx, __shfl_xor(mx, 32));
            float s = 0.f;
            #pragma unroll
            for (int mi = 0; mi < 4; ++mi) {
                #pragma unroll
                for (int r = 0; r < 4; ++r) {
                    const float p = __expf(ec[mi][r] - mx);
                    ec[mi][r] = p;
                    s += p;
                }
            }
            s += __shfl_xor(s, 16);
            s += __shfl_xor(s, 32);
            const float rs = 1.0f / s;
            #pragma unroll
            for (int mi = 0; mi < 4; ++mi) pf[mi][ni] = pack4s(ec[mi], rs);
        }
    }
    // qf/kf dead.

    // ===== proj v (reads LA), C rows = m =====
    s16x4 vf[4][2];
    {
        f32x4 acc[4][2];
        #pragma unroll
        for (int mi = 0; mi < 4; ++mi)
            #pragma unroll
            for (int nn = 0; nn < 2; ++nn) acc[mi][nn] = f32x4{0.f, 0.f, 0.f, 0.f};
        #pragma unroll
        for (int kk = 0; kk < 4; ++kk) {
            bf16x8 xa[4], wb[2];
            #pragma unroll
            for (int mi = 0; mi < 4; ++mi) xa[mi] = ldx(LA, mi * 16 + l16, kk);
            #pragma unroll
            for (int nn = 0; nn < 2; ++nn)
                wb[nn] = (MODE == 0) ? ldw(2, h * 32 + nn * 16 + l16, kk)
                                     : cvt8(Wv + (h * 32 + nn * 16 + l16) * DIM + kk * 32 + k8 * 8);
            #pragma unroll
            for (int mi = 0; mi < 4; ++mi)
                #pragma unroll
                for (int nn = 0; nn < 2; ++nn) acc[mi][nn] = MFMA32(xa[mi], wb[nn], acc[mi][nn]);
        }
        #pragma unroll
        for (int mi = 0; mi < 4; ++mi)
            #pragma unroll
            for (int nn = 0; nn < 2; ++nn) vf[mi][nn] = pack4(acc[mi][nn]);
    }

    // ===== PV via MFMA16 (lane-local) =====
    f32x4 o_[4][2];  // row = l = ni*16 + k8*4 + r, col = d = h*32 + nn*16 + l16
    #pragma unroll
    for (int ni = 0; ni < 4; ++ni) {
        #pragma unroll
        for (int nn = 0; nn < 2; ++nn) {
            f32x4 c = {0.f, 0.f, 0.f, 0.f};
            #pragma unroll
            for (int mi = 0; mi < 4; ++mi) c = MFMA16(pf[mi][ni], vf[mi][nn], c);
            o_[ni][nn] = c;
        }
    }

    // ===== OH -> LB; Wo frag loads overlap the barrier =====
    #pragma unroll
    for (int ni = 0; ni < 4; ++ni) {
        #pragma unroll
        for (int nn = 0; nn < 2; ++nn) {
            const int d = h * 32 + nn * 16 + l16;
            #pragma unroll
            for (int r = 0; r < 4; ++r) {
                const int row = ni * 16 + k8 * 4 + r;
                *reinterpret_cast<u16*>(LB + xo256(row, d * 2)) = bfbits(o_[ni][nn][r]);
            }
        }
    }
    bf16x8 aw[2][4];
    #pragma unroll
    for (int m2 = 0; m2 < 2; ++m2) {
        const int o = (wave * 2 + m2) * 16 + l16;
        #pragma unroll
        for (int kk = 0; kk < 4; ++kk)
            aw[m2][kk] = (MODE == 0) ? ldw(3, o, kk)
                                     : cvt8(Wo + o * DIM + kk * 32 + k8 * 8);
    }
    __syncthreads();  // barrier 4

    // ===== out-proj swapped: out^T[o][l]; float4 store + fused bias ==========
    #pragma unroll
    for (int ni = 0; ni < 4; ++ni) {
        const int l = ni * 16 + l16;
        bf16x8 bx[4];
        #pragma unroll
        for (int kk = 0; kk < 4; ++kk)
            bx[kk] = *reinterpret_cast<const bf16x8*>(LB + xo256(l, kk * 64 + k8 * 16));
        #pragma unroll
        for (int m2 = 0; m2 < 2; ++m2) {
            f32x4 c = {0.f, 0.f, 0.f, 0.f};
            #pragma unroll
            for (int kk = 0; kk < 4; ++kk) c = MFMA32(aw[m2][kk], bx[kk], c);
            if (l < TOK) {
                const int o0 = (wave * 2 + m2) * 16 + k8 * 4;
                const float4 bias = *reinterpret_cast<const float4*>(bo + o0);
                float4 st;
                st.x = c[0] + bias.x;
                st.y = c[1] + bias.y;
                st.z = c[2] + bias.z;
                st.w = c[3] + bias.w;
                *reinterpret_cast<float4*>(op + l * DIM + o0) = st;
            }
        }
    }
}

extern "C" void kernel_launch(void* const* d_in, const int* in_sizes, int n_in,
                              void* d_out, int out_size, void* d_ws, size_t ws_size,
                              hipStream_t stream) {
    const float* q    = (const float*)d_in[0];
    const float* k    = (const float*)d_in[1];
    const float* v    = (const float*)d_in[2];
    const float* mask = (const float*)d_in[3];
    const float* Wq   = (const float*)d_in[4];
    const float* Wk   = (const float*)d_in[5];
    const float* Wv   = (const float*)d_in[6];
    const float* Wo   = (const float*)d_in[7];
    const float* bo   = (const float*)d_in[8];
    const float* rel  = (const float*)d_in[9];
    float* out = (float*)d_out;

    const int B = in_sizes[0] / (TOK * DIM);  // 8192 windows
    const size_t FUSED_BYTES = (size_t)NWIN * NHEAD * 64 * 64 * sizeof(u16);  // 32 MB
    const size_t W_BYTES     = (size_t)4 * DIM * DIM * sizeof(u16);           // 128 KB
    const size_t BIAS_BYTES  = (size_t)NHEAD * 64 * 64 * sizeof(float);       // 64 KB

    if (ws_size >= FUSED_BYTES + W_BYTES) {
        u16* fmtbl = (u16*)d_ws;
        u16* wtbl  = (u16*)((char*)d_ws + FUSED_BYTES);
        fused_pre_kernel<<<dim3(NWIN * NHEAD * 64 * 64 / 256), dim3(256), 0, stream>>>(
            mask, rel, fmtbl);
        wcvt_kernel<<<dim3(4 * DIM * DIM / 256), dim3(256), 0, stream>>>(Wq, Wk, Wv, Wo, wtbl);
        winattn_kernel<0><<<dim3(B), dim3(256), 0, stream>>>(q, k, v, mask, Wq, Wk, Wv, Wo,
                                                             bo, wtbl, fmtbl, nullptr, out);
    } else {
        float* btbl = (float*)d_ws;  // 64 KB, proven to fit
        bias_pre_kernel<<<dim3(NHEAD * 64 * 64 / 256), dim3(256), 0, stream>>>(rel, btbl);
        winattn_kernel<1><<<dim3(B), dim3(256), 0, stream>>>(q, k, v, mask, Wq, Wk, Wv, Wo,
                                                             bo, nullptr, nullptr, btbl, out);
    }
}